// Round 4
// baseline (542.556 us; speedup 1.0000x reference)
//
#include <hip/hip_runtime.h>
#include <stdint.h>
#include <stddef.h>

#define BM 128
#define BN 128
#define BK 64

typedef __bf16 bf16x8 __attribute__((ext_vector_type(8)));
typedef float floatx16 __attribute__((ext_vector_type(16)));

// round-to-nearest-even f32 -> bf16 bits
__device__ inline unsigned short f2bf(float f) {
    union { float f; unsigned int u; } v; v.f = f;
    unsigned int u = v.u;
    return (unsigned short)((u + 0x7fffu + ((u >> 16) & 1u)) >> 16);
}

// One launch converts both x and w (concatenated logical range).
__global__ void cvt_two(const float* __restrict__ x, const float* __restrict__ w,
                        unsigned short* __restrict__ xb, unsigned short* __restrict__ wb,
                        int nx4, int ntot4) {
    int i = blockIdx.x * blockDim.x + threadIdx.x;
    int stride = gridDim.x * blockDim.x;
    for (int idx = i; idx < ntot4; idx += stride) {
        const float4* src; ushort4* dst; int j;
        if (idx < nx4) { src = (const float4*)x; dst = (ushort4*)xb; j = idx; }
        else           { src = (const float4*)w; dst = (ushort4*)wb; j = idx - nx4; }
        float4 f = src[j];
        ushort4 o;
        o.x = f2bf(f.x); o.y = f2bf(f.y); o.z = f2bf(f.z); o.w = f2bf(f.w);
        dst[j] = o;
    }
}

// y[m,n] = sum_k A[m,k]*B[n,k] + bias[n]
// A: [M,K] bf16, B: [N,K] bf16 (K-major), C: [M,N] fp32.
// LDS: 16B-granule XOR swizzle (granule g of row r at phys g^(r&7)); staging
// permutes the GLOBAL source so global_load_lds destinations stay
// lane-contiguous. 0 bank conflicts (verified R2/R3).
// Compute: 32x32x16 bf16 MFMA, 2x2 per wave (64x64 wave tile).
__global__ void gemm_bt_bias(const unsigned short* __restrict__ A,
                             const unsigned short* __restrict__ B,
                             const float* __restrict__ bias,
                             float* __restrict__ C,
                             int M, int N, int K) {
    __shared__ __align__(16) unsigned short As[BM * BK]; // 16 KB, swizzled
    __shared__ __align__(16) unsigned short Bs[BN * BK]; // 16 KB, swizzled

    const int tid  = threadIdx.x;
    const int lane = tid & 63;
    const int wave = tid >> 6;          // 0..3

    const int bm = blockIdx.y * BM;
    const int bn = blockIdx.x * BN;

    // Staging: 16 chunks of 1 KB per tile; wave w owns chunks w*4..w*4+3.
    // Chunk c, lane l -> phys granule c*64+l = (row c*8+(l>>3), phys pg=l&7)
    // holding logical granule g = (l&7)^(l>>3)  [lane-only].
    const unsigned short* gA[4];
    const unsigned short* gB[4];
    const unsigned short* lA[4];
    const unsigned short* lB[4];
    {
        const int g = (lane & 7) ^ (lane >> 3);
        const int rsub = lane >> 3;
#pragma unroll
        for (int i = 0; i < 4; ++i) {
            int c = wave * 4 + i;
            int r = c * 8 + rsub;
            gA[i] = A + (size_t)(bm + r) * K + g * 8;
            gB[i] = B + (size_t)(bn + r) * K + g * 8;
            lA[i] = As + c * 512;
            lB[i] = Bs + c * 512;
        }
    }

    const int lc = lane & 31;           // A row / B col / C col
    const int lh = lane >> 5;           // k-half select

    const int wm = (wave >> 1) * 64;
    const int wn = (wave & 1) * 64;

    floatx16 acc[2][2];
#pragma unroll
    for (int mi = 0; mi < 2; ++mi)
#pragma unroll
        for (int ni = 0; ni < 2; ++ni)
            acc[mi][ni] = (floatx16)(0.f);

    for (int k0 = 0; k0 < K; k0 += BK) {
#pragma unroll
        for (int i = 0; i < 4; ++i) {
            __builtin_amdgcn_global_load_lds(
                (const __attribute__((address_space(1))) void*)(gA[i]),
                (__attribute__((address_space(3))) void*)(lA[i]), 16, 0, 0);
            __builtin_amdgcn_global_load_lds(
                (const __attribute__((address_space(1))) void*)(gB[i]),
                (__attribute__((address_space(3))) void*)(lB[i]), 16, 0, 0);
            gA[i] += BK;
            gB[i] += BK;
        }
        __syncthreads();

#pragma unroll
        for (int ks = 0; ks < 4; ++ks) {
            // logical k-granule = ks*2 + lh; phys = g ^ (row&7), row&7 == lc&7
            const int pg = ((ks << 1) | lh) ^ (lc & 7);
            bf16x8 af[2], bfr[2];
#pragma unroll
            for (int mi = 0; mi < 2; ++mi)
                af[mi] = *(const bf16x8*)(As + (wm + mi * 32 + lc) * BK + pg * 8);
#pragma unroll
            for (int ni = 0; ni < 2; ++ni)
                bfr[ni] = *(const bf16x8*)(Bs + (wn + ni * 32 + lc) * BK + pg * 8);
#pragma unroll
            for (int mi = 0; mi < 2; ++mi)
#pragma unroll
                for (int ni = 0; ni < 2; ++ni)
                    acc[mi][ni] = __builtin_amdgcn_mfma_f32_32x32x16_bf16(
                        af[mi], bfr[ni], acc[mi][ni], 0, 0, 0);
        }
        __syncthreads();
    }

    // epilogue: C/D layout col=lane&31, row=(reg&3)+8*(reg>>2)+4*(lane>>5)
    // (m74/m101-verified)
#pragma unroll
    for (int ni = 0; ni < 2; ++ni) {
        int n = bn + wn + ni * 32 + lc;
        float bv = bias[n];
#pragma unroll
        for (int mi = 0; mi < 2; ++mi) {
            int m0 = bm + wm + mi * 32 + 4 * lh;
#pragma unroll
            for (int g = 0; g < 4; ++g) {
#pragma unroll
                for (int r = 0; r < 4; ++r) {
                    int row = m0 + 8 * g + r;
                    C[(size_t)row * N + n] = acc[mi][ni][g * 4 + r] + bv;
                }
            }
        }
    }
}

extern "C" void kernel_launch(void* const* d_in, const int* in_sizes, int n_in,
                              void* d_out, int out_size, void* d_ws, size_t ws_size,
                              hipStream_t stream) {
    const float* x    = (const float*)d_in[0];  // [M,K]
    const float* w    = (const float*)d_in[1];  // [N,K]
    const float* bias = (const float*)d_in[2];  // [N]
    float* out = (float*)d_out;

    const int N = in_sizes[2];             // 4096
    const int K = in_sizes[1] / N;         // 4096
    const int M = in_sizes[0] / K;         // 8192

    unsigned short* xb = (unsigned short*)d_ws;              // [M,K] bf16
    unsigned short* wb = xb + (size_t)M * K;                 // [N,K] bf16

    const int nx4 = (M * K) / 4, nw4 = (N * K) / 4;
    cvt_two<<<4096, 256, 0, stream>>>(x, w, xb, wb, nx4, nx4 + nw4);

    dim3 grid(N / BN, M / BM);
    gemm_bt_bias<<<grid, 256, 0, stream>>>(xb, wb, bias, out, M, N, K);
}